// Round 1
// baseline (639.493 us; speedup 1.0000x reference)
//
#include <hip/hip_runtime.h>

#define NODES 50000
#define EDGES 800000
#define HID   128
#define HEADS 4
// DK = 32, scale = 1/sqrt(32)
#define SCORE_SCALE 0.17677669529663687f

// ---------------------------------------------------------------------------
// Q/K projection: out = x @ W + b.  blockIdx.z selects (W_Q,b_Q,q) / (W_K,b_K,k).
// Block: 256 threads -> 32 rows x 128 cols per block.
// x tile staged transposed in LDS (pad 33 -> conflict-free), W streamed from L2.
// ---------------------------------------------------------------------------
__global__ __launch_bounds__(256) void gemm_qk(
    const float* __restrict__ x,
    const float* __restrict__ Wq, const float* __restrict__ bq,
    const float* __restrict__ Wk, const float* __restrict__ bk,
    float* __restrict__ q, float* __restrict__ k, int n)
{
    const float* W = (blockIdx.z == 0) ? Wq : Wk;
    const float* b = (blockIdx.z == 0) ? bq : bk;
    float* out     = (blockIdx.z == 0) ? q  : k;

    __shared__ float sXt[HID][33];   // [col][row_local], 32 rows, padded

    const int t    = threadIdx.x;
    const int row0 = blockIdx.x * 32;

    // stage x tile (transposed)
    #pragma unroll
    for (int i = 0; i < 16; ++i) {
        int idx = i * 256 + t;           // 0..4095
        int rl  = idx >> 7;              // row_local 0..31
        int c   = idx & 127;             // col
        int row = row0 + rl;
        float v = (row < n) ? x[(size_t)row * HID + c] : 0.f;
        sXt[c][rl] = v;
    }
    __syncthreads();

    const int c4 = t & 31;     // col group: cols 4*c4 .. 4*c4+3
    const int rg = t >> 5;     // row group: rows rg*4 .. rg*4+3

    float4 bb = *(const float4*)(b + c4 * 4);
    float4 acc0 = bb, acc1 = bb, acc2 = bb, acc3 = bb;

    #pragma unroll 4
    for (int kk = 0; kk < HID; ++kk) {
        float4 w = *(const float4*)(W + (size_t)kk * HID + c4 * 4);
        float x0 = sXt[kk][rg * 4 + 0];
        float x1 = sXt[kk][rg * 4 + 1];
        float x2 = sXt[kk][rg * 4 + 2];
        float x3 = sXt[kk][rg * 4 + 3];
        acc0.x += x0 * w.x; acc0.y += x0 * w.y; acc0.z += x0 * w.z; acc0.w += x0 * w.w;
        acc1.x += x1 * w.x; acc1.y += x1 * w.y; acc1.z += x1 * w.z; acc1.w += x1 * w.w;
        acc2.x += x2 * w.x; acc2.y += x2 * w.y; acc2.z += x2 * w.z; acc2.w += x2 * w.w;
        acc3.x += x3 * w.x; acc3.y += x3 * w.y; acc3.z += x3 * w.z; acc3.w += x3 * w.w;
    }

    int rowb = row0 + rg * 4;
    if (rowb + 0 < n) *(float4*)(out + (size_t)(rowb + 0) * HID + c4 * 4) = acc0;
    if (rowb + 1 < n) *(float4*)(out + (size_t)(rowb + 1) * HID + c4 * 4) = acc1;
    if (rowb + 2 < n) *(float4*)(out + (size_t)(rowb + 2) * HID + c4 * 4) = acc2;
    if (rowb + 3 < n) *(float4*)(out + (size_t)(rowb + 3) * HID + c4 * 4) = acc3;
}

// ---------------------------------------------------------------------------
// out-degree histogram over src
// ---------------------------------------------------------------------------
__global__ __launch_bounds__(256) void hist_kernel(
    const int* __restrict__ ei, int* __restrict__ deg)
{
    int i = blockIdx.x * 256 + threadIdx.x;
    if (i < EDGES) atomicAdd(&deg[ei[i]], 1);   // src = ei[0..E)
}

// ---------------------------------------------------------------------------
// per-edge scores -> exp -> evals[e][h], atomic segment-sum into nsum[dst][h]
// Half-wave (32 lanes) per edge: lane l32 holds float4 at dim 4*l32,
// head = l32/8; butterfly-reduce within 8-lane groups.
// ---------------------------------------------------------------------------
__global__ __launch_bounds__(256) void score_kernel(
    const float* __restrict__ q, const float* __restrict__ k,
    const int* __restrict__ ei,
    float* __restrict__ evals, float* __restrict__ nsum)
{
    const int t    = threadIdx.x;
    const int lane = t & 63;
    const int sub  = lane >> 5;          // which edge in this wave
    const int l32  = lane & 31;
    const int edge = blockIdx.x * 8 + ((t >> 6) << 1) + sub;  // 8 edges / block

    const int src = ei[edge];
    const int dst = ei[EDGES + edge];

    float4 qv = *(const float4*)(q + (size_t)src * HID + l32 * 4);
    float4 kv = *(const float4*)(k + (size_t)dst * HID + l32 * 4);
    float p = qv.x * kv.x + qv.y * kv.y + qv.z * kv.z + qv.w * kv.w;

    p += __shfl_xor(p, 1);
    p += __shfl_xor(p, 2);
    p += __shfl_xor(p, 4);

    if ((l32 & 7) == 0) {
        int head = l32 >> 3;
        float e = expf(p * SCORE_SCALE);
        evals[(size_t)edge * HEADS + head] = e;
        atomicAdd(&nsum[(size_t)dst * HEADS + head], e);
    }
}

// ---------------------------------------------------------------------------
// exclusive scan of deg -> off (and cursor copy). Single block, 1024 threads.
// ---------------------------------------------------------------------------
__global__ __launch_bounds__(1024) void scan_kernel(
    const int* __restrict__ deg, int* __restrict__ off,
    int* __restrict__ cur, int n)
{
    __shared__ int sdata[1024];
    __shared__ int s_base;
    const int t = threadIdx.x;
    if (t == 0) s_base = 0;
    __syncthreads();

    for (int start = 0; start < n; start += 1024) {
        int i = start + t;
        int v = (i < n) ? deg[i] : 0;
        sdata[t] = v;
        __syncthreads();
        #pragma unroll
        for (int o = 1; o < 1024; o <<= 1) {
            int add = (t >= o) ? sdata[t - o] : 0;
            __syncthreads();
            sdata[t] += add;
            __syncthreads();
        }
        int excl = sdata[t] - v;
        if (i < n) {
            int o = s_base + excl;
            off[i] = o;
            cur[i] = o;
        }
        __syncthreads();
        if (t == 1023) s_base += sdata[1023];
        __syncthreads();
    }
    if (t == 0) off[n] = s_base;
}

// ---------------------------------------------------------------------------
// head-mean attention + CSR fill (col = dst, val = att_mean)
// ---------------------------------------------------------------------------
__global__ __launch_bounds__(256) void finalize_kernel(
    const int* __restrict__ ei,
    const float* __restrict__ evals, const float* __restrict__ nsum,
    int* __restrict__ cur, int* __restrict__ ccol, float* __restrict__ cval)
{
    int e = blockIdx.x * 256 + threadIdx.x;
    if (e >= EDGES) return;
    int src = ei[e];
    int dst = ei[EDGES + e];
    float4 ev = *(const float4*)(evals + (size_t)e * HEADS);
    float4 sv = *(const float4*)(nsum  + (size_t)dst * HEADS);
    float am = 0.25f * (ev.x / (sv.x + 1e-16f) + ev.y / (sv.y + 1e-16f) +
                        ev.z / (sv.z + 1e-16f) + ev.w / (sv.w + 1e-16f));
    int pos = atomicAdd(&cur[src], 1);
    ccol[pos] = dst;
    cval[pos] = am;
}

// ---------------------------------------------------------------------------
// one Euler step: out[i,:] = 0.75*in[i,:] + 0.25 * sum_j val[j]*in[col[j],:]
// Wave per node, lane per float2 (128 dims).
// ---------------------------------------------------------------------------
__global__ __launch_bounds__(256) void spmv_kernel(
    const float* __restrict__ in, float* __restrict__ outp,
    const int* __restrict__ off, const int* __restrict__ col,
    const float* __restrict__ val, int n)
{
    const int w    = (blockIdx.x * 256 + threadIdx.x) >> 6;  // node
    const int lane = threadIdx.x & 63;
    if (w >= n) return;

    const int beg = off[w];
    const int end = off[w + 1];

    float ax = 0.f, ay = 0.f;
    for (int j = beg; j < end; j += 64) {
        int cnt = end - j; if (cnt > 64) cnt = 64;
        int   c = 0; float v = 0.f;
        if (lane < cnt) { c = col[j + lane]; v = val[j + lane]; }
        for (int jj = 0; jj < cnt; ++jj) {
            int   cc = __shfl(c, jj);
            float vv = __shfl(v, jj);
            float2 s = *(const float2*)(in + (size_t)cc * HID + lane * 2);
            ax += vv * s.x;
            ay += vv * s.y;
        }
    }
    float2 xi = *(const float2*)(in + (size_t)w * HID + lane * 2);
    float2 o;
    o.x = 0.75f * xi.x + 0.25f * ax;
    o.y = 0.75f * xi.y + 0.25f * ay;
    *(float2*)(outp + (size_t)w * HID + lane * 2) = o;
}

// ---------------------------------------------------------------------------
extern "C" void kernel_launch(void* const* d_in, const int* in_sizes, int n_in,
                              void* d_out, int out_size, void* d_ws, size_t ws_size,
                              hipStream_t stream)
{
    (void)in_sizes; (void)n_in; (void)out_size; (void)ws_size;

    const float* x  = (const float*)d_in[0];
    const float* Wq = (const float*)d_in[1];
    const float* bq = (const float*)d_in[2];
    const float* Wk = (const float*)d_in[3];
    const float* bk = (const float*)d_in[4];
    const int*   ei = (const int*)d_in[5];
    float* out = (float*)d_out;

    const int N = NODES, E = EDGES;

    char* ws = (char*)d_ws;
    float* q     = (float*)ws;  ws += (size_t)N * HID * 4;      // 25.6 MB
    float* kbuf  = (float*)ws;  ws += (size_t)N * HID * 4;      // 25.6 MB
    float* evals = (float*)ws;  ws += (size_t)E * HEADS * 4;    // 12.8 MB
    float* nsum  = (float*)ws;  ws += (size_t)N * HEADS * 4;    // 0.8 MB
    int*   deg   = (int*)ws;    ws += (size_t)N * 4;            // 0.2 MB
    int*   off   = (int*)ws;    ws += (size_t)(N + 1) * 4 + 12; // 0.2 MB (padded)
    int*   cur   = (int*)ws;    ws += (size_t)N * 4;            // 0.2 MB
    int*   ccol  = (int*)ws;    ws += (size_t)E * 4;            // 3.2 MB
    float* cval  = (float*)ws;  ws += (size_t)E * 4;            // 3.2 MB
    float* st    = (float*)ws;  ws += (size_t)N * HID * 4;      // 25.6 MB

    // zero nsum + deg (contiguous)
    hipMemsetAsync(nsum, 0, (size_t)N * HEADS * 4 + (size_t)N * 4, stream);

    // Q/K projections
    gemm_qk<<<dim3((N + 31) / 32, 1, 2), 256, 0, stream>>>(x, Wq, bq, Wk, bk, q, kbuf, N);

    // degree histogram (by src)
    hist_kernel<<<E / 256, 256, 0, stream>>>(ei, deg);

    // per-edge scores -> exp -> segment sums
    score_kernel<<<E / 8, 256, 0, stream>>>(q, kbuf, ei, evals, nsum);

    // CSR offsets
    scan_kernel<<<1, 1024, 0, stream>>>(deg, off, cur, N);

    // attention mean + CSR fill
    finalize_kernel<<<E / 256, 256, 0, stream>>>(ei, evals, nsum, cur, ccol, cval);

    // 4 Euler steps (ping-pong: x -> st -> out -> st -> out)
    spmv_kernel<<<(N * 64 + 255) / 256, 256, 0, stream>>>(x,   st,  off, ccol, cval, N);
    spmv_kernel<<<(N * 64 + 255) / 256, 256, 0, stream>>>(st,  out, off, ccol, cval, N);
    spmv_kernel<<<(N * 64 + 255) / 256, 256, 0, stream>>>(out, st,  off, ccol, cval, N);
    spmv_kernel<<<(N * 64 + 255) / 256, 256, 0, stream>>>(st,  out, off, ccol, cval, N);
}

// Round 2
// 445.254 us; speedup vs baseline: 1.4362x; 1.4362x over previous
//
#include <hip/hip_runtime.h>

#define NODES 50000
#define EDGES 800000
#define HID   128
#define HEADS 4
// DK = 32, scale = 1/sqrt(32)
#define SCORE_SCALE 0.17677669529663687f

typedef unsigned int  u32;
typedef unsigned short u16;

// round-to-nearest-even f32 -> bf16
__device__ __forceinline__ u16 f2bf(float f) {
    u32 u = __builtin_bit_cast(u32, f);
    return (u16)((u + 0x7FFFu + ((u >> 16) & 1u)) >> 16);
}
__device__ __forceinline__ float bflo(u32 u) {            // low ushort -> f32
    return __builtin_bit_cast(float, u << 16);
}
__device__ __forceinline__ float bfhi(u32 u) {            // high ushort -> f32
    return __builtin_bit_cast(float, u & 0xFFFF0000u);
}
__device__ __forceinline__ float bdot2(u32 a, u32 b) {
    return bflo(a) * bflo(b) + bfhi(a) * bfhi(b);
}

// ---------------------------------------------------------------------------
// Q/K projection: out = bf16(x @ W + b). blockIdx.z picks Q / K.
// z==0 blocks additionally emit bf16 copy of x (from the staged LDS tile).
// ---------------------------------------------------------------------------
__global__ __launch_bounds__(256) void gemm_qk(
    const float* __restrict__ x,
    const float* __restrict__ Wq, const float* __restrict__ bq,
    const float* __restrict__ Wk, const float* __restrict__ bk,
    u16* __restrict__ qb, u16* __restrict__ kb, u16* __restrict__ xb, int n)
{
    const float* W = (blockIdx.z == 0) ? Wq : Wk;
    const float* b = (blockIdx.z == 0) ? bq : bk;
    u16* out       = (blockIdx.z == 0) ? qb : kb;

    __shared__ float sXt[HID][33];   // [col][row_local], 32 rows, padded

    const int t    = threadIdx.x;
    const int row0 = blockIdx.x * 32;

    #pragma unroll
    for (int i = 0; i < 16; ++i) {
        int idx = i * 256 + t;
        int rl  = idx >> 7;
        int c   = idx & 127;
        int row = row0 + rl;
        sXt[c][rl] = (row < n) ? x[(size_t)row * HID + c] : 0.f;
    }
    __syncthreads();

    // bf16 copy of x (only from the z==0 grid slice)
    if (blockIdx.z == 0) {
        #pragma unroll
        for (int i = 0; i < 16; ++i) {
            int idx = i * 256 + t;
            int rl  = idx >> 7;
            int c   = idx & 127;
            int row = row0 + rl;
            if (row < n) xb[(size_t)row * HID + c] = f2bf(sXt[c][rl]);
        }
    }

    const int c4 = t & 31;     // cols 4*c4 .. 4*c4+3
    const int rg = t >> 5;     // rows rg*4 .. rg*4+3

    float4 bb = *(const float4*)(b + c4 * 4);
    float4 acc0 = bb, acc1 = bb, acc2 = bb, acc3 = bb;

    #pragma unroll 4
    for (int kk = 0; kk < HID; ++kk) {
        float4 w = *(const float4*)(W + (size_t)kk * HID + c4 * 4);
        float x0 = sXt[kk][rg * 4 + 0];
        float x1 = sXt[kk][rg * 4 + 1];
        float x2 = sXt[kk][rg * 4 + 2];
        float x3 = sXt[kk][rg * 4 + 3];
        acc0.x += x0 * w.x; acc0.y += x0 * w.y; acc0.z += x0 * w.z; acc0.w += x0 * w.w;
        acc1.x += x1 * w.x; acc1.y += x1 * w.y; acc1.z += x1 * w.z; acc1.w += x1 * w.w;
        acc2.x += x2 * w.x; acc2.y += x2 * w.y; acc2.z += x2 * w.z; acc2.w += x2 * w.w;
        acc3.x += x3 * w.x; acc3.y += x3 * w.y; acc3.z += x3 * w.z; acc3.w += x3 * w.w;
    }

    int rowb = row0 + rg * 4;
    #define WR(r, acc) if (rowb + r < n) { \
        ushort4 pv; pv.x = f2bf(acc.x); pv.y = f2bf(acc.y); \
        pv.z = f2bf(acc.z); pv.w = f2bf(acc.w); \
        *(ushort4*)(out + (size_t)(rowb + r) * HID + c4 * 4) = pv; }
    WR(0, acc0) WR(1, acc1) WR(2, acc2) WR(3, acc3)
    #undef WR
}

// ---------------------------------------------------------------------------
// out-degree histogram over src
// ---------------------------------------------------------------------------
__global__ __launch_bounds__(256) void hist_kernel(
    const int* __restrict__ ei, int* __restrict__ deg)
{
    int i = blockIdx.x * 256 + threadIdx.x;
    if (i < EDGES) atomicAdd(&deg[ei[i]], 1);
}

// ---------------------------------------------------------------------------
// per-edge scores (bf16 q/k) -> exp -> evals[e][h], atomic sums into nsum.
// 16 lanes per edge: lane covers dims l16*8..+7 (uint4 = 8 bf16); head = l16/4.
// ---------------------------------------------------------------------------
__global__ __launch_bounds__(256) void score_kernel(
    const u16* __restrict__ qb, const u16* __restrict__ kb,
    const int* __restrict__ ei,
    float* __restrict__ evals, float* __restrict__ nsum)
{
    const int t    = threadIdx.x;
    const int l16  = t & 15;
    const int edge = blockIdx.x * 16 + (t >> 4);

    const int src = ei[edge];
    const int dst = ei[EDGES + edge];

    uint4 qv = *(const uint4*)(qb + (size_t)src * HID + l16 * 8);
    uint4 kv = *(const uint4*)(kb + (size_t)dst * HID + l16 * 8);
    float p = bdot2(qv.x, kv.x) + bdot2(qv.y, kv.y) +
              bdot2(qv.z, kv.z) + bdot2(qv.w, kv.w);

    p += __shfl_xor(p, 1);
    p += __shfl_xor(p, 2);

    if ((l16 & 3) == 0) {
        int head = l16 >> 2;
        float e = __expf(p * SCORE_SCALE);
        evals[(size_t)edge * HEADS + head] = e;
        atomicAdd(&nsum[(size_t)dst * HEADS + head], e);
    }
}

// ---------------------------------------------------------------------------
// two-level exclusive scan of deg -> off (+cursor)
// ---------------------------------------------------------------------------
__global__ __launch_bounds__(1024) void scan1(
    const int* __restrict__ deg, int* __restrict__ off,
    int* __restrict__ part, int n)
{
    __shared__ int sd[1024];
    int t = threadIdx.x, i = blockIdx.x * 1024 + t;
    int v = (i < n) ? deg[i] : 0;
    sd[t] = v;
    __syncthreads();
    #pragma unroll
    for (int o = 1; o < 1024; o <<= 1) {
        int a = (t >= o) ? sd[t - o] : 0;
        __syncthreads();
        sd[t] += a;
        __syncthreads();
    }
    if (i < n) off[i] = sd[t] - v;       // block-local exclusive
    if (t == 1023) part[blockIdx.x] = sd[1023];
}

__global__ __launch_bounds__(64) void scan2(int* __restrict__ part,
                                            int* __restrict__ off_n, int nb)
{
    int t = threadIdx.x;                 // 64 threads, nb <= 64
    int v = (t < nb) ? part[t] : 0;
    int orig = v;
    #pragma unroll
    for (int o = 1; o < 64; o <<= 1) {
        int a = __shfl_up(v, o);
        if (t >= o) v += a;
    }
    if (t < nb) part[t] = v - orig;      // exclusive block bases
    if (t == 63) *off_n = v;             // grand total
}

__global__ __launch_bounds__(1024) void scan3(
    int* __restrict__ off, int* __restrict__ cur,
    const int* __restrict__ part, int n)
{
    int i = blockIdx.x * 1024 + threadIdx.x;
    if (i < n) {
        int o = off[i] + part[blockIdx.x];
        off[i] = o;
        cur[i] = o;
    }
}

// ---------------------------------------------------------------------------
// head-mean attention + CSR fill (col = dst, val = att_mean)
// ---------------------------------------------------------------------------
__global__ __launch_bounds__(256) void finalize_kernel(
    const int* __restrict__ ei,
    const float* __restrict__ evals, const float* __restrict__ nsum,
    int* __restrict__ cur, int* __restrict__ ccol, float* __restrict__ cval)
{
    int e = blockIdx.x * 256 + threadIdx.x;
    if (e >= EDGES) return;
    int src = ei[e];
    int dst = ei[EDGES + e];
    float4 ev = *(const float4*)(evals + (size_t)e * HEADS);
    float4 sv = *(const float4*)(nsum  + (size_t)dst * HEADS);
    float am = 0.25f * (ev.x / (sv.x + 1e-16f) + ev.y / (sv.y + 1e-16f) +
                        ev.z / (sv.z + 1e-16f) + ev.w / (sv.w + 1e-16f));
    int pos = atomicAdd(&cur[src], 1);
    ccol[pos] = dst;
    cval[pos] = am;
}

// ---------------------------------------------------------------------------
// Euler step: out[i,:] = 0.75*in[i,:] + 0.25 * sum_j val[j]*in_bf[col[j],:]
// Wave per node; gathers from bf16 state copy (256 B/row); fp32 master row.
// Steps 1-3 also emit a packed bf16 copy of the output.
// ---------------------------------------------------------------------------
template<int WRITE_BF>
__global__ __launch_bounds__(256) void spmv_kernel(
    const float* __restrict__ inf, const u16* __restrict__ inb,
    float* __restrict__ outf, u16* __restrict__ outb,
    const int* __restrict__ off, const int* __restrict__ col,
    const float* __restrict__ val, int n)
{
    const int w    = (blockIdx.x * 256 + threadIdx.x) >> 6;
    const int lane = threadIdx.x & 63;
    if (w >= n) return;

    const int beg = off[w];
    const int end = off[w + 1];

    float ax = 0.f, ay = 0.f;
    for (int j = beg; j < end; j += 64) {
        int cnt = end - j; if (cnt > 64) cnt = 64;
        int   c = 0; float v = 0.f;
        if (lane < cnt) { c = col[j + lane]; v = val[j + lane]; }
        for (int jj = 0; jj < cnt; ++jj) {
            int   cc = __shfl(c, jj);
            float vv = __shfl(v, jj);
            u32 s = *(const u32*)(inb + (size_t)cc * HID + lane * 2);
            ax += vv * bflo(s);
            ay += vv * bfhi(s);
        }
    }
    float2 xi = *(const float2*)(inf + (size_t)w * HID + lane * 2);
    float2 o;
    o.x = 0.75f * xi.x + 0.25f * ax;
    o.y = 0.75f * xi.y + 0.25f * ay;
    *(float2*)(outf + (size_t)w * HID + lane * 2) = o;
    if (WRITE_BF) {
        u32 pb = ((u32)f2bf(o.y) << 16) | (u32)f2bf(o.x);
        *(u32*)(outb + (size_t)w * HID + lane * 2) = pb;
    }
}

// ---------------------------------------------------------------------------
extern "C" void kernel_launch(void* const* d_in, const int* in_sizes, int n_in,
                              void* d_out, int out_size, void* d_ws, size_t ws_size,
                              hipStream_t stream)
{
    (void)in_sizes; (void)n_in; (void)out_size; (void)ws_size;

    const float* x  = (const float*)d_in[0];
    const float* Wq = (const float*)d_in[1];
    const float* bq = (const float*)d_in[2];
    const float* Wk = (const float*)d_in[3];
    const float* bk = (const float*)d_in[4];
    const int*   ei = (const int*)d_in[5];
    float* out = (float*)d_out;

    const int N = NODES, E = EDGES;
    const size_t ROWB_F = (size_t)N * HID * 4;   // 25.6 MB fp32 state
    const size_t ROWB_B = (size_t)N * HID * 2;   // 12.8 MB bf16 state

    char* ws = (char*)d_ws;
    // region A: qb|kb  -- dead after score -- reused as stA_f
    u16*   qb    = (u16*)(ws);
    u16*   kb    = (u16*)(ws + ROWB_B);
    float* stA_f = (float*)(ws);
    ws += 2 * ROWB_B;
    // region B: xb|evals -- dead after spmv step 1 / finalize -- reused as stB_f
    u16*   xb    = (u16*)(ws);
    float* evals = (float*)(ws + ROWB_B);        // E*4*4 = 12.8 MB
    float* stB_f = (float*)(xb);
    ws += 2 * ROWB_B;
    u16*   stA_b = (u16*)ws;  ws += ROWB_B;
    u16*   stB_b = (u16*)ws;  ws += ROWB_B;
    float* nsum  = (float*)ws; ws += (size_t)N * HEADS * 4;  // 0.8 MB
    int*   deg   = (int*)ws;   ws += (size_t)N * 4;          // 0.2 MB (memset with nsum)
    int*   off   = (int*)ws;   ws += ((size_t)(N + 1) * 4 + 255) & ~255ull;
    int*   cur   = (int*)ws;   ws += (size_t)N * 4;
    int*   part  = (int*)ws;   ws += 256;
    int*   ccol  = (int*)ws;   ws += (size_t)E * 4;          // 3.2 MB
    float* cval  = (float*)ws; ws += (size_t)E * 4;          // 3.2 MB

    // zero nsum + deg (contiguous)
    hipMemsetAsync(nsum, 0, (size_t)N * HEADS * 4 + (size_t)N * 4, stream);

    // Q/K projections (bf16 out) + bf16 copy of x
    gemm_qk<<<dim3((N + 31) / 32, 1, 2), 256, 0, stream>>>(
        x, Wq, bq, Wk, bk, qb, kb, xb, N);

    // degree histogram (by src)
    hist_kernel<<<E / 256, 256, 0, stream>>>(ei, deg);

    // per-edge scores -> exp -> segment sums
    score_kernel<<<E / 16, 256, 0, stream>>>(qb, kb, ei, evals, nsum);

    // CSR offsets: two-level scan
    const int nb = (N + 1023) / 1024;            // 49
    scan1<<<nb, 1024, 0, stream>>>(deg, off, part, N);
    scan2<<<1, 64, 0, stream>>>(part, off + N, nb);
    scan3<<<nb, 1024, 0, stream>>>(off, cur, part, N);

    // attention mean + CSR fill
    finalize_kernel<<<E / 256, 256, 0, stream>>>(ei, evals, nsum, cur, ccol, cval);

    // 4 Euler steps (bf16 gathers; region overlays honored by ordering)
    const int sg = (N * 64 + 255) / 256;
    spmv_kernel<1><<<sg, 256, 0, stream>>>(x,     xb,    stA_f, stA_b, off, ccol, cval, N);
    spmv_kernel<1><<<sg, 256, 0, stream>>>(stA_f, stA_b, stB_f, stB_b, off, ccol, cval, N);
    spmv_kernel<1><<<sg, 256, 0, stream>>>(stB_f, stB_b, stA_f, stA_b, off, ccol, cval, N);
    spmv_kernel<0><<<sg, 256, 0, stream>>>(stA_f, stA_b, out,   nullptr, off, ccol, cval, N);
}

// Round 3
// 334.615 us; speedup vs baseline: 1.9111x; 1.3306x over previous
//
#include <hip/hip_runtime.h>

#define NODES 50000
#define EDGES 800000
#define HID   128
#define HEADS 4
// DK = 32, scale = 1/sqrt(32)
#define SCORE_SCALE 0.17677669529663687f

typedef unsigned int   u32;
typedef unsigned short u16;

typedef __attribute__((ext_vector_type(8))) short bf16x8;
typedef __attribute__((ext_vector_type(4))) float f32x4;

// round-to-nearest-even f32 -> bf16
__device__ __forceinline__ u16 f2bf(float f) {
    u32 u = __builtin_bit_cast(u32, f);
    return (u16)((u + 0x7FFFu + ((u >> 16) & 1u)) >> 16);
}
__device__ __forceinline__ float bflo(u32 u) { return __builtin_bit_cast(float, u << 16); }
__device__ __forceinline__ float bfhi(u32 u) { return __builtin_bit_cast(float, u & 0xFFFF0000u); }
__device__ __forceinline__ float bdot2(u32 a, u32 b) {
    return bflo(a) * bflo(b) + bfhi(a) * bfhi(b);
}

// ---------------------------------------------------------------------------
// W prep: Wt[n][k] = bf16(W[k][n]), both 128x128. 2 matrices.
// ---------------------------------------------------------------------------
__global__ __launch_bounds__(256) void wprep(
    const float* __restrict__ Wq, const float* __restrict__ Wk,
    u16* __restrict__ Wqt, u16* __restrict__ Wkt)
{
    int e   = blockIdx.x * 256 + threadIdx.x;   // 0..32767
    int mat = e >> 14;
    int idx = e & 16383;
    int k  = idx >> 7;
    int nn = idx & 127;
    const float* W = mat ? Wk : Wq;
    u16*        Wt = mat ? Wkt : Wqt;
    Wt[nn * 128 + k] = f2bf(W[idx]);
}

// ---------------------------------------------------------------------------
// MFMA Q/K projection. Block = 4 waves, wave = one 16-row tile, both matrices.
// A-frag: x rows converted to bf16 in-register (also emits xb copy).
// B-frag: uint4 straight from L2-resident Wt (bf16, [n][k] layout).
// Layouts (16x16x32): A row=l&15, k=(l>>4)*8+j ; B col=l&15, k=(l>>4)*8+j ;
// D col=l&15, row=(l>>4)*4+reg.
// ---------------------------------------------------------------------------
__global__ __launch_bounds__(256) void gemm_qk_mfma(
    const float* __restrict__ x,
    const u16* __restrict__ Wqt, const float* __restrict__ bq,
    const u16* __restrict__ Wkt, const float* __restrict__ bk,
    u16* __restrict__ qb, u16* __restrict__ kb, u16* __restrict__ xb, int n)
{
    const int l  = threadIdx.x & 63;
    const int w  = threadIdx.x >> 6;
    const int lr = l & 15;          // A-row in tile / B,D col in col-block
    const int kg = l >> 4;          // k-group 0..3

    const int arow   = blockIdx.x * 64 + w * 16 + lr;
    const bool av    = (arow < n);
    const int  arowc = av ? arow : (n - 1);

    bf16x8 afrag[4];
    #pragma unroll
    for (int ks = 0; ks < 4; ++ks) {
        const float* px = x + (size_t)arowc * HID + ks * 32 + kg * 8;
        float4 p0 = *(const float4*)px;
        float4 p1 = *(const float4*)(px + 4);
        uint4 pk;
        pk.x = (u32)f2bf(p0.x) | ((u32)f2bf(p0.y) << 16);
        pk.y = (u32)f2bf(p0.z) | ((u32)f2bf(p0.w) << 16);
        pk.z = (u32)f2bf(p1.x) | ((u32)f2bf(p1.y) << 16);
        pk.w = (u32)f2bf(p1.z) | ((u32)f2bf(p1.w) << 16);
        afrag[ks] = __builtin_bit_cast(bf16x8, pk);
        if (av) *(uint4*)(xb + (size_t)arow * HID + ks * 32 + kg * 8) = pk;
    }

    #pragma unroll
    for (int mat = 0; mat < 2; ++mat) {
        const u16*   Wt   = mat ? Wkt : Wqt;
        const float* bias = mat ? bk : bq;
        u16*         outp = mat ? kb : qb;

        #pragma unroll
        for (int cb = 0; cb < 8; ++cb) {
            float bc = bias[cb * 16 + lr];
            f32x4 acc = {bc, bc, bc, bc};
            #pragma unroll
            for (int ks = 0; ks < 4; ++ks) {
                bf16x8 bfrag = __builtin_bit_cast(bf16x8,
                    *(const uint4*)(Wt + (size_t)(cb * 16 + lr) * 128 + ks * 32 + kg * 8));
                acc = __builtin_amdgcn_mfma_f32_16x16x32_bf16(afrag[ks], bfrag, acc, 0, 0, 0);
            }
            #pragma unroll
            for (int reg = 0; reg < 4; ++reg) {
                int gr = blockIdx.x * 64 + w * 16 + kg * 4 + reg;
                if (gr < n) outp[(size_t)gr * HID + cb * 16 + lr] = f2bf(acc[reg]);
            }
        }
    }
}

// ---------------------------------------------------------------------------
// out-degree histogram over src
// ---------------------------------------------------------------------------
__global__ __launch_bounds__(256) void hist_kernel(
    const int* __restrict__ ei, int* __restrict__ deg)
{
    int i = blockIdx.x * 256 + threadIdx.x;
    if (i < EDGES) atomicAdd(&deg[ei[i]], 1);
}

// ---------------------------------------------------------------------------
// per-edge scores (bf16 q/k) -> exp -> evals[e][h], atomic sums into nsum.
// 16 lanes per edge: lane covers dims l16*8..+7 (uint4 = 8 bf16); head = l16/4.
// ---------------------------------------------------------------------------
__global__ __launch_bounds__(256) void score_kernel(
    const u16* __restrict__ qb, const u16* __restrict__ kb,
    const int* __restrict__ ei,
    float* __restrict__ evals, float* __restrict__ nsum)
{
    const int t    = threadIdx.x;
    const int l16  = t & 15;
    const int edge = blockIdx.x * 16 + (t >> 4);

    const int src = ei[edge];
    const int dst = ei[EDGES + edge];

    uint4 qv = *(const uint4*)(qb + (size_t)src * HID + l16 * 8);
    uint4 kv = *(const uint4*)(kb + (size_t)dst * HID + l16 * 8);
    float p = bdot2(qv.x, kv.x) + bdot2(qv.y, kv.y) +
              bdot2(qv.z, kv.z) + bdot2(qv.w, kv.w);

    p += __shfl_xor(p, 1);
    p += __shfl_xor(p, 2);

    if ((l16 & 3) == 0) {
        int head = l16 >> 2;
        float e = __expf(p * SCORE_SCALE);
        evals[(size_t)edge * HEADS + head] = e;
        atomicAdd(&nsum[(size_t)dst * HEADS + head], e);
    }
}

// ---------------------------------------------------------------------------
// two-level exclusive scan of deg -> off (+cursor)
// ---------------------------------------------------------------------------
__global__ __launch_bounds__(1024) void scan1(
    const int* __restrict__ deg, int* __restrict__ off,
    int* __restrict__ part, int n)
{
    __shared__ int sd[1024];
    int t = threadIdx.x, i = blockIdx.x * 1024 + t;
    int v = (i < n) ? deg[i] : 0;
    sd[t] = v;
    __syncthreads();
    #pragma unroll
    for (int o = 1; o < 1024; o <<= 1) {
        int a = (t >= o) ? sd[t - o] : 0;
        __syncthreads();
        sd[t] += a;
        __syncthreads();
    }
    if (i < n) off[i] = sd[t] - v;
    if (t == 1023) part[blockIdx.x] = sd[1023];
}

__global__ __launch_bounds__(64) void scan2(int* __restrict__ part,
                                            int* __restrict__ off_n, int nb)
{
    int t = threadIdx.x;
    int v = (t < nb) ? part[t] : 0;
    int orig = v;
    #pragma unroll
    for (int o = 1; o < 64; o <<= 1) {
        int a = __shfl_up(v, o);
        if (t >= o) v += a;
    }
    if (t < nb) part[t] = v - orig;
    if (t == 63) *off_n = v;
}

__global__ __launch_bounds__(1024) void scan3(
    int* __restrict__ off, int* __restrict__ cur,
    const int* __restrict__ part, int n)
{
    int i = blockIdx.x * 1024 + threadIdx.x;
    if (i < n) {
        int o = off[i] + part[blockIdx.x];
        off[i] = o;
        cur[i] = o;
    }
}

// ---------------------------------------------------------------------------
// head-mean attention + CSR fill (col = dst, val = att_mean)
// ---------------------------------------------------------------------------
__global__ __launch_bounds__(256) void finalize_kernel(
    const int* __restrict__ ei,
    const float* __restrict__ evals, const float* __restrict__ nsum,
    int* __restrict__ cur, int* __restrict__ ccol, float* __restrict__ cval)
{
    int e = blockIdx.x * 256 + threadIdx.x;
    if (e >= EDGES) return;
    int src = ei[e];
    int dst = ei[EDGES + e];
    float4 ev = *(const float4*)(evals + (size_t)e * HEADS);
    float4 sv = *(const float4*)(nsum  + (size_t)dst * HEADS);
    float am = 0.25f * (ev.x / (sv.x + 1e-16f) + ev.y / (sv.y + 1e-16f) +
                        ev.z / (sv.z + 1e-16f) + ev.w / (sv.w + 1e-16f));
    int pos = atomicAdd(&cur[src], 1);
    ccol[pos] = dst;
    cval[pos] = am;
}

// ---------------------------------------------------------------------------
// Euler step: out[i,:] = 0.75*in[i,:] + 0.25 * sum_j val[j]*in_bf[col[j],:]
// Wave per node; 8-deep batched gathers to overlap L3 latency.
// ---------------------------------------------------------------------------
template<int WRITE_BF>
__global__ __launch_bounds__(256) void spmv_kernel(
    const float* __restrict__ inf, const u16* __restrict__ inb,
    float* __restrict__ outf, u16* __restrict__ outb,
    const int* __restrict__ off, const int* __restrict__ col,
    const float* __restrict__ val, int n)
{
    const int w    = (blockIdx.x * 256 + threadIdx.x) >> 6;
    const int lane = threadIdx.x & 63;
    if (w >= n) return;

    const int beg = off[w];
    const int end = off[w + 1];

    float ax = 0.f, ay = 0.f;
    for (int j = beg; j < end; j += 64) {
        int cnt = end - j; if (cnt > 64) cnt = 64;
        int   c = 0; float v = 0.f;
        if (lane < cnt) { c = col[j + lane]; v = val[j + lane]; }

        int jj = 0;
        for (; jj + 8 <= cnt; jj += 8) {
            int cc[8]; float vv[8]; u32 s[8];
            #pragma unroll
            for (int u = 0; u < 8; ++u) { cc[u] = __shfl(c, jj + u); vv[u] = __shfl(v, jj + u); }
            #pragma unroll
            for (int u = 0; u < 8; ++u) s[u] = *(const u32*)(inb + (size_t)cc[u] * HID + lane * 2);
            #pragma unroll
            for (int u = 0; u < 8; ++u) { ax += vv[u] * bflo(s[u]); ay += vv[u] * bfhi(s[u]); }
        }
        for (; jj + 4 <= cnt; jj += 4) {
            int cc[4]; float vv[4]; u32 s[4];
            #pragma unroll
            for (int u = 0; u < 4; ++u) { cc[u] = __shfl(c, jj + u); vv[u] = __shfl(v, jj + u); }
            #pragma unroll
            for (int u = 0; u < 4; ++u) s[u] = *(const u32*)(inb + (size_t)cc[u] * HID + lane * 2);
            #pragma unroll
            for (int u = 0; u < 4; ++u) { ax += vv[u] * bflo(s[u]); ay += vv[u] * bfhi(s[u]); }
        }
        for (; jj < cnt; ++jj) {
            int   cc = __shfl(c, jj);
            float vv = __shfl(v, jj);
            u32 s = *(const u32*)(inb + (size_t)cc * HID + lane * 2);
            ax += vv * bflo(s);
            ay += vv * bfhi(s);
        }
    }
    float2 xi = *(const float2*)(inf + (size_t)w * HID + lane * 2);
    float2 o;
    o.x = 0.75f * xi.x + 0.25f * ax;
    o.y = 0.75f * xi.y + 0.25f * ay;
    *(float2*)(outf + (size_t)w * HID + lane * 2) = o;
    if (WRITE_BF) {
        u32 pb = ((u32)f2bf(o.y) << 16) | (u32)f2bf(o.x);
        *(u32*)(outb + (size_t)w * HID + lane * 2) = pb;
    }
}

// ---------------------------------------------------------------------------
extern "C" void kernel_launch(void* const* d_in, const int* in_sizes, int n_in,
                              void* d_out, int out_size, void* d_ws, size_t ws_size,
                              hipStream_t stream)
{
    (void)in_sizes; (void)n_in; (void)out_size; (void)ws_size;

    const float* x  = (const float*)d_in[0];
    const float* Wq = (const float*)d_in[1];
    const float* bq = (const float*)d_in[2];
    const float* Wk = (const float*)d_in[3];
    const float* bk = (const float*)d_in[4];
    const int*   ei = (const int*)d_in[5];
    float* out = (float*)d_out;

    const int N = NODES, E = EDGES;
    const size_t ROWB_B = (size_t)N * HID * 2;   // 12.8 MB bf16 state

    char* ws = (char*)d_ws;
    // region A: qb|kb  -- dead after score -- reused as stA_f
    u16*   qb    = (u16*)(ws);
    u16*   kb    = (u16*)(ws + ROWB_B);
    float* stA_f = (float*)(ws);
    ws += 2 * ROWB_B;
    // region B: xb|evals -- dead after spmv step 1 / finalize -- reused as stB_f
    u16*   xb    = (u16*)(ws);
    float* evals = (float*)(ws + ROWB_B);
    float* stB_f = (float*)(xb);
    ws += 2 * ROWB_B;
    u16*   stA_b = (u16*)ws;  ws += ROWB_B;
    u16*   stB_b = (u16*)ws;  ws += ROWB_B;
    float* nsum  = (float*)ws; ws += (size_t)N * HEADS * 4;
    int*   deg   = (int*)ws;   ws += (size_t)N * 4;
    int*   off   = (int*)ws;   ws += ((size_t)(N + 1) * 4 + 255) & ~255ull;
    int*   cur   = (int*)ws;   ws += (size_t)N * 4;
    int*   part  = (int*)ws;   ws += 256;
    int*   ccol  = (int*)ws;   ws += (size_t)E * 4;
    float* cval  = (float*)ws; ws += (size_t)E * 4;
    u16*   Wqt   = (u16*)ws;   ws += (size_t)128 * 128 * 2;
    u16*   Wkt   = (u16*)ws;   ws += (size_t)128 * 128 * 2;

    // zero nsum + deg (contiguous)
    hipMemsetAsync(nsum, 0, (size_t)N * HEADS * 4 + (size_t)N * 4, stream);

    // W -> bf16 transposed
    wprep<<<128, 256, 0, stream>>>(Wq, Wk, Wqt, Wkt);

    // Q/K projections via MFMA (bf16 out) + bf16 copy of x
    gemm_qk_mfma<<<(N + 63) / 64, 256, 0, stream>>>(
        x, Wqt, bq, Wkt, bk, qb, kb, xb, N);

    // degree histogram (by src)
    hist_kernel<<<E / 256, 256, 0, stream>>>(ei, deg);

    // per-edge scores -> exp -> segment sums
    score_kernel<<<E / 16, 256, 0, stream>>>(qb, kb, ei, evals, nsum);

    // CSR offsets: two-level scan
    const int nb = (N + 1023) / 1024;
    scan1<<<nb, 1024, 0, stream>>>(deg, off, part, N);
    scan2<<<1, 64, 0, stream>>>(part, off + N, nb);
    scan3<<<nb, 1024, 0, stream>>>(off, cur, part, N);

    // attention mean + CSR fill
    finalize_kernel<<<E / 256, 256, 0, stream>>>(ei, evals, nsum, cur, ccol, cval);

    // 4 Euler steps (bf16 gathers; region overlays honored by ordering)
    const int sg = (N * 64 + 255) / 256;
    spmv_kernel<1><<<sg, 256, 0, stream>>>(x,     xb,    stA_f, stA_b, off, ccol, cval, N);
    spmv_kernel<1><<<sg, 256, 0, stream>>>(stA_f, stA_b, stB_f, stB_b, off, ccol, cval, N);
    spmv_kernel<1><<<sg, 256, 0, stream>>>(stB_f, stB_b, stA_f, stA_b, off, ccol, cval, N);
    spmv_kernel<0><<<sg, 256, 0, stream>>>(stA_f, stA_b, out,   nullptr, off, ccol, cval, N);
}